// Round 2
// baseline (3120.286 us; speedup 1.0000x reference)
//
#include <hip/hip_runtime.h>

#define T 32
#define B 256

// ---------------- workspace byte offsets ----------------
//   w2t   float  [576][128]    OFF 0          (294,912 B)
//   w3t   double [1152][256]   OFF 294912     (2,359,296 B)
//   tcwt  double [768][256]    OFF 2654208    (1,572,864 B)
//   recwt double [256][256]    OFF 4227072    (524,288 B)
//   fc1wt double [256][128]    OFF 4751360    (262,144 B)
#define OFF_W2T   0
#define OFF_W3T   294912
#define OFF_TCWT  2654208
#define OFF_RECWT 4227072
#define OFF_FC1WT 4751360
#define OFF_S1    5013504      // uchar  [T][B][64][8][8]  33,554,432
#define OFF_POOL  38567936     // uchar  [T][B][128][9]     9,437,184 (4x pooled sum 0..4)
#define OFF_PSP3  48005120     // double [T][B][256]       16,777,216
#define OFF_S3    64782336     // uchar  [T][B][256]        2,097,152
#define OFF_PSPTC 66879488     // double [T][B][256]       16,777,216
#define OFF_TC    83656704     // uchar  [T][B][256]        2,097,152
#define OFF_R     85753856     // uchar  [T][B][256]        2,097,152
// total: 87,851,008 bytes

// ---------------- weight transposes (+ fp64 conversion for GEMM-ish layers) ----
__global__ __launch_bounds__(256) void k_prep(const float* __restrict__ c2w,
        const float* __restrict__ c3w, const float* __restrict__ tcw,
        const float* __restrict__ rcw, const float* __restrict__ f1w,
        float* __restrict__ w2t, double* __restrict__ w3t,
        double* __restrict__ tcwt, double* __restrict__ recwt,
        double* __restrict__ fc1wt) {
    int n = blockIdx.x * 256 + threadIdx.x;
    if (n < 73728) {                       // w2t[k][oc] <- conv2_w[oc][ic][3][3]
        int oc = n & 127, k = n >> 7;
        w2t[n] = c2w[(oc * 64 + k / 9) * 9 + k % 9];
    } else if (n < 368640) {               // w3t[k][oc] <- conv3_w[oc][ic][3][3]
        int m = n - 73728;
        int oc = m & 255, k = m >> 8;
        w3t[m] = (double)c3w[(oc * 128 + k / 9) * 9 + k % 9];
    } else if (n < 565248) {               // tcwt[j*256+k][oc] <- tc_w[j][oc][k]
        int m = n - 368640;
        int oc = m & 255, kp = m >> 8;
        int j = kp >> 8, k = kp & 255;
        tcwt[m] = (double)tcw[(j * 256 + oc) * 256 + k];
    } else if (n < 630784) {               // recwt[k][oc] <- rec_w[oc][k]
        int m = n - 565248;
        int oc = m & 255, k = m >> 8;
        recwt[m] = (double)rcw[oc * 256 + k];
    } else if (n < 663552) {               // fc1wt[k][oc] <- fc1_w[oc][k]
        int m = n - 630784;
        int oc = m & 127, k = m >> 7;
        fc1wt[m] = (double)f1w[oc * 256 + k];
    }
}

// ---------------- conv1 + LIF1 -> s1 spikes (bytes), fp64 state ----------------
__global__ __launch_bounds__(256) void k_conv1(const float* __restrict__ x,
        const float* __restrict__ w1, const float* __restrict__ b1,
        unsigned char* __restrict__ s1) {
    __shared__ float xl[3200];
    int b   = blockIdx.x >> 4;
    int oc  = ((blockIdx.x & 15) << 2) + (threadIdx.x >> 6);
    int pix = threadIdx.x & 63;
    int oy = pix >> 3, ox = pix & 7;
    const float* xb = x + b * 3200;        // input_data[b][0][10][10][T], t innermost
    for (int i = threadIdx.x; i < 3200; i += 256)
        xl[(i & 31) * 100 + (i >> 5)] = xb[i];   // LDS as [t][pos]
    double w[9];
#pragma unroll
    for (int j = 0; j < 9; ++j) w[j] = (double)w1[oc * 9 + j];
    double bias = (double)b1[oc];
    __syncthreads();
    double cur = 0.0, vlt = 0.0;
    int spk = 0;
    unsigned char* so = s1 + b * 4096 + oc * 64 + pix;
    for (int t = 0; t < T; ++t) {
        const float* xt = &xl[t * 100 + oy * 10 + ox];
        double z = bias;
#pragma unroll
        for (int ky = 0; ky < 3; ++ky)
#pragma unroll
            for (int kx = 0; kx < 3; ++kx)
                z = fma(w[ky * 3 + kx], (double)xt[ky * 10 + kx], z);
        cur = 0.5 * cur + z;
        vlt = (spk ? 0.0 : 0.75 * vlt) + cur;
        spk = (vlt > 0.5) ? 1 : 0;
        so[t * (B * 4096)] = (unsigned char)spk;
    }
}

// ---------------- conv2 + LIF2 + avgpool -> pooled sums, fp64 accumulation ------
// grid 256 (b) ; block 768 = 128 oc * 6 oy ; thread owns one output row (6 ox)
__global__ __launch_bounds__(768) void k_conv2(const unsigned char* __restrict__ s1,
        const float* __restrict__ w2t, const float* __restrict__ b2,
        unsigned char* __restrict__ pooled) {
    __shared__ __align__(16) float plane[4096];   // [ic][8][8]
    __shared__ __align__(16) float wt[9216];      // 8-ic weight group [8*9][128]
    __shared__ unsigned char spx[768];            // [oy][oc] 6-bit spike rows
    int b  = blockIdx.x;
    int oc = threadIdx.x & 127;
    int oy = threadIdx.x >> 7;                    // 0..5
    double bias = (double)b2[oc];
    double cur[6] = {0,0,0,0,0,0}, vlt[6] = {0,0,0,0,0,0};
    int spk[6] = {0,0,0,0,0,0};
    for (int t = 0; t < T; ++t) {
        if (threadIdx.x < 512) {                  // stage 4096 spike bytes -> floats
            const uint2* p = (const uint2*)(s1 + (size_t)(t * B + b) * 4096);
            uint2 v = p[threadIdx.x];
            int o = threadIdx.x * 8;
            plane[o + 0] = (float)(v.x & 255);        plane[o + 1] = (float)((v.x >> 8) & 255);
            plane[o + 2] = (float)((v.x >> 16) & 255); plane[o + 3] = (float)(v.x >> 24);
            plane[o + 4] = (float)(v.y & 255);        plane[o + 5] = (float)((v.y >> 8) & 255);
            plane[o + 6] = (float)((v.y >> 16) & 255); plane[o + 7] = (float)(v.y >> 24);
        }
#pragma unroll
        for (int ox = 0; ox < 6; ++ox) cur[ox] = 0.5 * cur[ox] + bias;
        for (int icg = 0; icg < 8; ++icg) {
            __syncthreads();                      // plane ready (icg=0) / wt consumers done
#pragma unroll
            for (int k = 0; k < 12; ++k)
                wt[k * 768 + threadIdx.x] = w2t[icg * 9216 + k * 768 + threadIdx.x];
            __syncthreads();
            for (int ic2 = 0; ic2 < 8; ++ic2) {
                double wd[9];
#pragma unroll
                for (int j = 0; j < 9; ++j) wd[j] = (double)wt[(ic2 * 9 + j) * 128 + oc];
                const float* pl = &plane[(icg * 8 + ic2) * 64 + oy * 8];
#pragma unroll
                for (int ky = 0; ky < 3; ++ky) {
                    float4 a = *(const float4*)&pl[ky * 8];
                    float4 c = *(const float4*)&pl[ky * 8 + 4];
                    double rd[8];
                    rd[0] = (double)a.x; rd[1] = (double)a.y; rd[2] = (double)a.z; rd[3] = (double)a.w;
                    rd[4] = (double)c.x; rd[5] = (double)c.y; rd[6] = (double)c.z; rd[7] = (double)c.w;
#pragma unroll
                    for (int kx = 0; kx < 3; ++kx)
#pragma unroll
                        for (int ox = 0; ox < 6; ++ox)
                            cur[ox] = fma(wd[ky * 3 + kx], rd[ox + kx], cur[ox]);
                }
            }
        }
        unsigned m = 0;
#pragma unroll
        for (int ox = 0; ox < 6; ++ox) {
            vlt[ox] = (spk[ox] ? 0.0 : 0.75 * vlt[ox]) + cur[ox];
            spk[ox] = (vlt[ox] > 0.5) ? 1 : 0;
            m |= ((unsigned)spk[ox]) << ox;
        }
        spx[oy * 128 + oc] = (unsigned char)m;
        __syncthreads();
        if ((oy & 1) == 0) {                      // 2x2 average pool -> integer sum 0..4
            unsigned pm = spx[(oy + 1) * 128 + oc];
            int py = oy >> 1;
            unsigned char* po = pooled + ((size_t)(t * B + b) * 128 + oc) * 9 + py * 3;
#pragma unroll
            for (int px = 0; px < 3; ++px) {
                unsigned s = ((m >> (2 * px)) & 1) + ((m >> (2 * px + 1)) & 1)
                           + ((pm >> (2 * px)) & 1) + ((pm >> (2 * px + 1)) & 1);
                po[px] = (unsigned char)s;
            }
        }
        __syncthreads();
    }
}

// ---------------- conv3 PSP: fp64 GEMM over all (t,b) rows ----------------
// grid 1024 = 32 t * 32 b-groups(8) ; block 256 (oc) ; K = 1152
__global__ __launch_bounds__(256) void k_c3psp(const unsigned char* __restrict__ pooled,
        const double* __restrict__ w3t, const float* __restrict__ b3,
        double* __restrict__ psp) {
    __shared__ __align__(16) float ap[8 * 1152];
    int t  = blockIdx.x >> 5;
    int bg = blockIdx.x & 31;
    int oc = threadIdx.x;
    const unsigned char* src = pooled + (size_t)(t * B + bg * 8) * 1152;
    for (int i = threadIdx.x; i < 8 * 1152; i += 256)
        ap[i] = 0.25f * (float)src[i];            // exact: n/4, n in 0..4
    __syncthreads();
    double bias = (double)b3[oc];
    double z[8];
#pragma unroll
    for (int j = 0; j < 8; ++j) z[j] = bias;
    for (int k = 0; k < 1152; k += 4) {
        double w0 = w3t[(k + 0) * 256 + oc];
        double w1 = w3t[(k + 1) * 256 + oc];
        double w2 = w3t[(k + 2) * 256 + oc];
        double w3 = w3t[(k + 3) * 256 + oc];
#pragma unroll
        for (int j = 0; j < 8; ++j) {
            float4 a = *(const float4*)&ap[j * 1152 + k];
            z[j] = fma(w0, (double)a.x, z[j]); z[j] = fma(w1, (double)a.y, z[j]);
            z[j] = fma(w2, (double)a.z, z[j]); z[j] = fma(w3, (double)a.w, z[j]);
        }
    }
    double* out = psp + (size_t)(t * B + bg * 8) * 256 + oc;
#pragma unroll
    for (int j = 0; j < 8; ++j) out[j * 256] = z[j];
}

// ---------------- sequential LIF sweep over [T][B*256] fp64 psp -> spikes -------
__global__ __launch_bounds__(256) void k_lif_flat(const double* __restrict__ psp,
        unsigned char* __restrict__ out) {
    int n = blockIdx.x * 256 + threadIdx.x;       // b*256+oc
    double cur = 0.0, vlt = 0.0;
    int spk = 0;
    for (int t = 0; t < T; ++t) {
        double z = psp[(size_t)t * 65536 + n];
        cur = 0.5 * cur + z;
        vlt = (spk ? 0.0 : 0.75 * vlt) + cur;
        spk = (vlt > 0.5) ? 1 : 0;
        out[(size_t)t * 65536 + n] = (unsigned char)spk;
    }
}

// ---------------- temporal-conv PSP (3-tap over s3 history), fp64 ----------------
__global__ __launch_bounds__(256) void k_tcpsp(const unsigned char* __restrict__ s3,
        const double* __restrict__ tcwt, const float* __restrict__ tcb,
        double* __restrict__ psp) {
    __shared__ __align__(16) float sv[8 * 768];
    int t  = blockIdx.x >> 5;
    int bg = blockIdx.x & 31;
    int oc = threadIdx.x;
    for (int i = threadIdx.x; i < 8 * 768; i += 256) {
        int bb = i / 768, kk = i - bb * 768;
        int j = kk >> 8, k = kk & 255;
        // slot j carries the j-th OLDEST buffered spike (W0 -> oldest)
        int src = (t >= 2) ? (t - 2 + j) : ((j <= t) ? j : -1);
        float v = 0.f;
        if (src >= 0) v = (float)s3[((size_t)src * B + bg * 8 + bb) * 256 + k];
        sv[i] = v;
    }
    double bias = (double)tcb[oc];
    if (t >= 1) bias += (double)tcb[256 + oc];
    if (t >= 2) bias += (double)tcb[512 + oc];
    __syncthreads();
    double z[8];
#pragma unroll
    for (int j = 0; j < 8; ++j) z[j] = bias;
    for (int k = 0; k < 768; k += 4) {
        double w0 = tcwt[(k + 0) * 256 + oc];
        double w1 = tcwt[(k + 1) * 256 + oc];
        double w2 = tcwt[(k + 2) * 256 + oc];
        double w3 = tcwt[(k + 3) * 256 + oc];
#pragma unroll
        for (int j = 0; j < 8; ++j) {
            float4 a = *(const float4*)&sv[j * 768 + k];
            z[j] = fma(w0, (double)a.x, z[j]); z[j] = fma(w1, (double)a.y, z[j]);
            z[j] = fma(w2, (double)a.z, z[j]); z[j] = fma(w3, (double)a.w, z[j]);
        }
    }
    double* out = psp + (size_t)(t * B + bg * 8) * 256 + oc;
#pragma unroll
    for (int j = 0; j < 8; ++j) out[j * 256] = z[j];
}

// ---------------- recurrent layer: per-sample block, t-sequential, sparse-skip ---
__global__ __launch_bounds__(256) void k_rec(const unsigned char* __restrict__ tcspk,
        const double* __restrict__ recwt, const float* __restrict__ rb,
        unsigned char* __restrict__ rspk) {
    __shared__ __align__(16) float rs[256];
    int b = blockIdx.x, oc = threadIdx.x;
    rs[oc] = 0.f;
    double bias = (double)rb[oc];
    double cur = 0.0, vlt = 0.0;
    int spk = 0;
    __syncthreads();
    for (int t = 0; t < T; ++t) {
        double z = bias + (double)tcspk[((size_t)t * B + b) * 256 + oc];
        for (int k = 0; k < 256; k += 4) {
            float4 s4 = *(const float4*)&rs[k];
            // spikes wave-uniform (same LDS addr) -> scalar branch skips weight load
            if (__builtin_amdgcn_readfirstlane(__float_as_int(s4.x))) z += recwt[(k + 0) * 256 + oc];
            if (__builtin_amdgcn_readfirstlane(__float_as_int(s4.y))) z += recwt[(k + 1) * 256 + oc];
            if (__builtin_amdgcn_readfirstlane(__float_as_int(s4.z))) z += recwt[(k + 2) * 256 + oc];
            if (__builtin_amdgcn_readfirstlane(__float_as_int(s4.w))) z += recwt[(k + 3) * 256 + oc];
        }
        cur = 0.5 * cur + z;
        vlt = (spk ? 0.0 : 0.75 * vlt) + cur;
        spk = (vlt > 0.5) ? 1 : 0;
        rspk[((size_t)t * B + b) * 256 + oc] = (unsigned char)spk;
        __syncthreads();
        rs[oc] = (float)spk;
        __syncthreads();
    }
}

// ---------------- fc1 + LIF + fc2 accumulate -> d_out, fp64 ----------------
__global__ __launch_bounds__(128) void k_fc(const unsigned char* __restrict__ rspk,
        const double* __restrict__ fc1wt, const float* __restrict__ f1b,
        const float* __restrict__ fc2w, const float* __restrict__ tsw,
        float* __restrict__ out) {
    __shared__ __align__(16) float rv[256];
    __shared__ float f1buf[128];
    int b = blockIdx.x, oc = threadIdx.x;
    double bias = (double)f1b[oc];
    double cur = 0.0, vlt = 0.0, acc = 0.0;
    int spk = 0;
    for (int t = 0; t < T; ++t) {
        const unsigned char* rp = rspk + ((size_t)t * B + b) * 256;
        rv[oc]       = (float)rp[oc];
        rv[oc + 128] = (float)rp[oc + 128];
        __syncthreads();
        double z = bias;
        for (int k = 0; k < 256; k += 4) {
            float4 s4 = *(const float4*)&rv[k];
            if (__builtin_amdgcn_readfirstlane(__float_as_int(s4.x))) z += fc1wt[(k + 0) * 128 + oc];
            if (__builtin_amdgcn_readfirstlane(__float_as_int(s4.y))) z += fc1wt[(k + 1) * 128 + oc];
            if (__builtin_amdgcn_readfirstlane(__float_as_int(s4.z))) z += fc1wt[(k + 2) * 128 + oc];
            if (__builtin_amdgcn_readfirstlane(__float_as_int(s4.w))) z += fc1wt[(k + 3) * 128 + oc];
        }
        cur = 0.5 * cur + z;
        vlt = (spk ? 0.0 : 0.75 * vlt) + cur;
        spk = (vlt > 0.5) ? 1 : 0;
        f1buf[oc] = (float)spk;
        __syncthreads();
        if (oc < 2) {
            double s = 0.0;
            for (int k = 0; k < 128; ++k)
                s = fma((double)f1buf[k], (double)fc2w[oc * 128 + k], s);
            acc = fma(s, (double)tsw[t], acc);
        }
        __syncthreads();
    }
    if (oc < 2) out[b * 2 + oc] = (float)acc;
}

extern "C" void kernel_launch(void* const* d_in, const int* in_sizes, int n_in,
                              void* d_out, int out_size, void* d_ws, size_t ws_size,
                              hipStream_t stream) {
    const float* x   = (const float*)d_in[0];
    const float* c1w = (const float*)d_in[1];
    const float* c1b = (const float*)d_in[2];
    const float* c2w = (const float*)d_in[3];
    const float* c2b = (const float*)d_in[4];
    const float* c3w = (const float*)d_in[5];
    const float* c3b = (const float*)d_in[6];
    const float* tcw = (const float*)d_in[7];
    const float* tcb = (const float*)d_in[8];
    const float* rcw = (const float*)d_in[9];
    const float* rcb = (const float*)d_in[10];
    const float* f1w = (const float*)d_in[11];
    const float* f1b = (const float*)d_in[12];
    const float* f2w = (const float*)d_in[13];
    const float* tsw = (const float*)d_in[14];

    char* ws = (char*)d_ws;
    float*  w2t           = (float*)(ws + OFF_W2T);
    double* w3t           = (double*)(ws + OFF_W3T);
    double* tcwt          = (double*)(ws + OFF_TCWT);
    double* recwt         = (double*)(ws + OFF_RECWT);
    double* fc1wt         = (double*)(ws + OFF_FC1WT);
    unsigned char* s1     = (unsigned char*)(ws + OFF_S1);
    unsigned char* pool   = (unsigned char*)(ws + OFF_POOL);
    double* psp3          = (double*)(ws + OFF_PSP3);
    unsigned char* s3     = (unsigned char*)(ws + OFF_S3);
    double* psptc         = (double*)(ws + OFF_PSPTC);
    unsigned char* tcs    = (unsigned char*)(ws + OFF_TC);
    unsigned char* rsp    = (unsigned char*)(ws + OFF_R);

    k_prep    <<<2592, 256, 0, stream>>>(c2w, c3w, tcw, rcw, f1w, w2t, w3t, tcwt, recwt, fc1wt);
    k_conv1   <<<4096, 256, 0, stream>>>(x, c1w, c1b, s1);
    k_conv2   <<<256,  768, 0, stream>>>(s1, w2t, c2b, pool);
    k_c3psp   <<<1024, 256, 0, stream>>>(pool, w3t, c3b, psp3);
    k_lif_flat<<<256,  256, 0, stream>>>(psp3, s3);
    k_tcpsp   <<<1024, 256, 0, stream>>>(s3, tcwt, tcb, psptc);
    k_lif_flat<<<256,  256, 0, stream>>>(psptc, tcs);
    k_rec     <<<256,  256, 0, stream>>>(tcs, recwt, rcb, rsp);
    k_fc      <<<256,  128, 0, stream>>>(rsp, fc1wt, f1b, f2w, tsw, (float*)d_out);
}

// Round 3
// 2235.427 us; speedup vs baseline: 1.3958x; 1.3958x over previous
//
#include <hip/hip_runtime.h>

#define T 32
#define B 256

typedef int v4i __attribute__((ext_vector_type(4)));

// ---------------- workspace byte offsets ----------------
#define OFF_BD    0            // int8  [5][128][576] conv2 weight digits   368,640
#define OFF_W3T   368640       // double [1152][256]                      2,359,296
#define OFF_TCWT  2727936      // double [768][256]                       1,572,864
#define OFF_RECWT 4300800      // double [256][256]                         524,288
#define OFF_FC1WT 4825088      // double [256][128]                         262,144
#define OFF_S1    5087232      // uchar [T][B][pix 64][ic 64]            33,554,432
#define OFF_POOL  38641664     // uchar [T][B][128][9]                    9,437,184
#define OFF_PSP3  48078848     // double [T][B][256]                     16,777,216
#define OFF_S3    64856064     // uchar [T][B][256]                       2,097,152
#define OFF_PSPTC 66953216     // double [T][B][256]                     16,777,216
#define OFF_TC    83730432     // uchar [T][B][256]                       2,097,152
#define OFF_R     85827584     // uchar [T][B][256]                       2,097,152
// total 87,924,736 bytes

// ---------------- fp64 weight transposes (c3 / tc / rec / fc1) ----------------
__global__ __launch_bounds__(256) void k_prep(const float* __restrict__ c3w,
        const float* __restrict__ tcw, const float* __restrict__ rcw,
        const float* __restrict__ f1w, double* __restrict__ w3t,
        double* __restrict__ tcwt, double* __restrict__ recwt,
        double* __restrict__ fc1wt) {
    int n = blockIdx.x * 256 + threadIdx.x;
    if (n < 294912) {                      // w3t[k][oc] <- conv3_w[oc][ic][3][3], k=ic*9+win
        int oc = n & 255, k = n >> 8;
        w3t[n] = (double)c3w[(oc * 128 + k / 9) * 9 + k % 9];
    } else if (n < 491520) {               // tcwt[j*256+k][oc] <- tc_w[j][oc][k]
        int m = n - 294912;
        int oc = m & 255, kp = m >> 8;
        int j = kp >> 8, k = kp & 255;
        tcwt[m] = (double)tcw[(j * 256 + oc) * 256 + k];
    } else if (n < 557056) {               // recwt[k][oc] <- rec_w[oc][k]
        int m = n - 491520;
        int oc = m & 255, k = m >> 8;
        recwt[m] = (double)rcw[oc * 256 + k];
    } else if (n < 589824) {               // fc1wt[k][oc] <- fc1_w[oc][k]
        int m = n - 557056;
        int oc = m & 127, k = m >> 7;
        fc1wt[m] = (double)f1w[oc * 256 + k];
    }
}

// ---------------- conv2 weight digit decomposition -----------------------------
// Bd[d][oc][k], k = (ky*3+kx)*64 + ic. W = rint(w * 2^38), 5 signed base-256 digits.
__global__ __launch_bounds__(256) void k_prep2(const float* __restrict__ c2w,
        signed char* __restrict__ Bd) {
    int idx = blockIdx.x * 256 + threadIdx.x;      // 73728 = 128 oc * 576 k
    if (idx >= 73728) return;
    int oc = idx / 576, kpos = idx - oc * 576;
    int kk = kpos >> 6, ic = kpos & 63;
    int ky = kk / 3, kx = kk - ky * 3;
    float w = c2w[((oc * 64 + ic) * 3 + ky) * 3 + kx];
    long long W = (long long)rint((double)w * 274877906944.0);   // 2^38
#pragma unroll
    for (int d = 0; d < 4; ++d) {
        int dig = (int)(((W + 128) & 255) - 128);
        Bd[d * 73728 + idx] = (signed char)dig;
        W = (W - dig) >> 8;
    }
    Bd[4 * 73728 + idx] = (signed char)W;
}

// ---------------- conv1 + LIF1 -> s1 [t][b][pix][ic], fp64 state ----------------
// grid 256 (b) ; block 256 = 64 oc(lanes) x 4 pixel-groups ; thread owns 16 pixels
__global__ __launch_bounds__(256) void k_conv1(const float* __restrict__ x,
        const float* __restrict__ w1, const float* __restrict__ b1,
        unsigned char* __restrict__ s1) {
    __shared__ float xl[3200];
    int b  = blockIdx.x;
    int oc = threadIdx.x & 63;
    int pg = threadIdx.x >> 6;              // 0..3
    const float* xb = x + b * 3200;         // input_data[b][0][10][10][T], t innermost
    for (int i = threadIdx.x; i < 3200; i += 256)
        xl[(i & 31) * 100 + (i >> 5)] = xb[i];   // LDS [t][pos]
    double wd[9];
#pragma unroll
    for (int j = 0; j < 9; ++j) wd[j] = (double)w1[oc * 9 + j];
    double bias = (double)b1[oc];
    __syncthreads();
    double cur[16], vlt[16];
    unsigned spkb = 0;
#pragma unroll
    for (int i = 0; i < 16; ++i) { cur[i] = 0.0; vlt[i] = 0.0; }
    for (int t = 0; t < T; ++t) {
#pragma unroll
        for (int i = 0; i < 16; ++i) {
            int pix = pg * 16 + i;
            int oy = pix >> 3, ox = pix & 7;
            const float* xt = &xl[t * 100 + oy * 10 + ox];
            double z = bias;
#pragma unroll
            for (int ky = 0; ky < 3; ++ky)
#pragma unroll
                for (int kx = 0; kx < 3; ++kx)
                    z = fma(wd[ky * 3 + kx], (double)xt[ky * 10 + kx], z);
            cur[i] = 0.5 * cur[i] + z;
            int s = (spkb >> i) & 1;
            vlt[i] = (s ? 0.0 : 0.75 * vlt[i]) + cur[i];
            s = (vlt[i] > 0.5) ? 1 : 0;
            spkb = (spkb & ~(1u << i)) | ((unsigned)s << i);
            s1[((size_t)(t * B + b) * 64 + pix) * 64 + oc] = (unsigned char)s;
        }
    }
}

// ---------------- conv2 via exact i8-digit MFMA + in-block LIF + avgpool --------
// grid B*9 (sample x pool-window) ; block 256 (4 waves)
// GEMM: M=128 rows (t*4+px), N=128 oc (two 64-halves), K=576 ((ky,kx)*64+ic)
__global__ __launch_bounds__(256) void k_conv2(const unsigned char* __restrict__ s1,
        const signed char* __restrict__ Bd, const float* __restrict__ cb2,
        unsigned char* __restrict__ pooled) {
    __shared__ double pl[2][4][4][64];     // [tile][t-sub q][px][oc]  (oc contiguous: no conflicts)
    __shared__ unsigned smask[4][64];
    const int b    = blockIdx.x / 9;
    const int w    = blockIdx.x - b * 9;
    const int wy   = w / 3, wx = w - wy * 3;
    const int wave = threadIdx.x >> 6, lane = threadIdx.x & 63;
    const int col  = lane & 15, quad = lane >> 4;
    const int tq   = (lane & 15) >> 2;      // A-row: t-offset within tile
    const int apx  = lane & 3;              // A-row: px
    const int apy  = apx >> 1, apxx = apx & 1;
    const int oc_l = threadIdx.x & 63;      // epilogue neuron mapping
    const int px_e = threadIdx.x >> 6;
    const unsigned char* s1b = s1 + (size_t)b * 4096;
    const double scl[5] = { 0x1p-38, 0x1p-30, 0x1p-22, 0x1p-14, 0x1p-6 };

    for (int nh = 0; nh < 2; ++nh) {
        const int ocb = nh * 64 + wave * 16;                     // GEMM-role oc base
        const signed char* Bw = Bd + (size_t)(ocb + col) * 576 + quad * 16;
        double cur = 0.0, vlt = 0.0;                             // epilogue-role LIF state
        int spk = 0;
        unsigned bits = 0;
        double bias = (double)cb2[nh * 64 + oc_l];

        for (int mp = 0; mp < 4; ++mp) {                         // M-tile pairs (t ascending)
            v4i acc[5][2];
#pragma unroll
            for (int d = 0; d < 5; ++d) {
                acc[d][0] = (v4i){0, 0, 0, 0};
                acc[d][1] = (v4i){0, 0, 0, 0};
            }
#pragma unroll
            for (int ky = 0; ky < 3; ++ky) {
#pragma unroll
                for (int kx = 0; kx < 3; ++kx) {
                    const int kk = ky * 3 + kx;
                    const int pix = (2 * wy + apy + ky) * 8 + (2 * wx + apxx + kx);
                    v4i Af[2];
#pragma unroll
                    for (int j = 0; j < 2; ++j) {
                        int t = (2 * mp + j) * 4 + tq;
                        Af[j] = *(const v4i*)(s1b + (size_t)t * (B * 4096) + pix * 64 + quad * 16);
                    }
#pragma unroll
                    for (int d = 0; d < 5; ++d) {
                        v4i Bf = *(const v4i*)(Bw + d * 73728 + kk * 64);
                        acc[d][0] = __builtin_amdgcn_mfma_i32_16x16x64_i8(Af[0], Bf, acc[d][0], 0, 0, 0);
                        acc[d][1] = __builtin_amdgcn_mfma_i32_16x16x64_i8(Af[1], Bf, acc[d][1], 0, 0, 0);
                    }
                }
            }
            __syncthreads();                 // previous m-pair's pl fully consumed
#pragma unroll
            for (int j = 0; j < 2; ++j)
#pragma unroll
                for (int r = 0; r < 4; ++r) {
                    double p = 0.0;
#pragma unroll
                    for (int d = 0; d < 5; ++d)
                        p = fma((double)acc[d][j][r], scl[d], p);
                    // C/D layout: col=lane&15 (oc), row=quad*4+r -> t=4m+quad, px=r
                    pl[j][quad][r][wave * 16 + col] = p;
                }
            __syncthreads();
            // LIF advance: 8 timesteps, each thread owns neuron (oc_l, px_e)
#pragma unroll
            for (int j = 0; j < 2; ++j)
#pragma unroll
                for (int q = 0; q < 4; ++q) {
                    int t = (2 * mp + j) * 4 + q;
                    double z = bias + pl[j][q][px_e][oc_l];
                    cur = 0.5 * cur + z;
                    vlt = (spk ? 0.0 : 0.75 * vlt) + cur;
                    spk = (vlt > 0.5) ? 1 : 0;
                    bits |= ((unsigned)spk) << t;
                }
        }
        smask[px_e][oc_l] = bits;
        __syncthreads();
        if (px_e == 0) {                     // 2x2 avgpool -> integer sum 0..4
            unsigned m0 = smask[0][oc_l], m1 = smask[1][oc_l];
            unsigned m2 = smask[2][oc_l], m3 = smask[3][oc_l];
            int ocg = nh * 64 + oc_l;
            for (int t = 0; t < T; ++t) {
                unsigned s = ((m0 >> t) & 1) + ((m1 >> t) & 1) + ((m2 >> t) & 1) + ((m3 >> t) & 1);
                pooled[((size_t)(t * B + b) * 128 + ocg) * 9 + w] = (unsigned char)s;
            }
        }
        __syncthreads();
    }
}

// ---------------- conv3 PSP: fp64 GEMM over all (t,b) rows ----------------
__global__ __launch_bounds__(256) void k_c3psp(const unsigned char* __restrict__ pooled,
        const double* __restrict__ w3t, const float* __restrict__ b3,
        double* __restrict__ psp) {
    __shared__ __align__(16) float ap[8 * 1152];
    int t  = blockIdx.x >> 5;
    int bg = blockIdx.x & 31;
    int oc = threadIdx.x;
    const unsigned char* src = pooled + (size_t)(t * B + bg * 8) * 1152;
    for (int i = threadIdx.x; i < 8 * 1152; i += 256)
        ap[i] = 0.25f * (float)src[i];            // exact: n/4, n in 0..4
    __syncthreads();
    double bias = (double)b3[oc];
    double z[8];
#pragma unroll
    for (int j = 0; j < 8; ++j) z[j] = bias;
    for (int k = 0; k < 1152; k += 4) {
        double w0 = w3t[(k + 0) * 256 + oc];
        double w1 = w3t[(k + 1) * 256 + oc];
        double w2 = w3t[(k + 2) * 256 + oc];
        double w3 = w3t[(k + 3) * 256 + oc];
#pragma unroll
        for (int j = 0; j < 8; ++j) {
            float4 a = *(const float4*)&ap[j * 1152 + k];
            z[j] = fma(w0, (double)a.x, z[j]); z[j] = fma(w1, (double)a.y, z[j]);
            z[j] = fma(w2, (double)a.z, z[j]); z[j] = fma(w3, (double)a.w, z[j]);
        }
    }
    double* out = psp + (size_t)(t * B + bg * 8) * 256 + oc;
#pragma unroll
    for (int j = 0; j < 8; ++j) out[j * 256] = z[j];
}

// ---------------- sequential LIF sweep over [T][B*256] fp64 psp -> spikes -------
__global__ __launch_bounds__(256) void k_lif_flat(const double* __restrict__ psp,
        unsigned char* __restrict__ out) {
    int n = blockIdx.x * 256 + threadIdx.x;
    double cur = 0.0, vlt = 0.0;
    int spk = 0;
    for (int t = 0; t < T; ++t) {
        double z = psp[(size_t)t * 65536 + n];
        cur = 0.5 * cur + z;
        vlt = (spk ? 0.0 : 0.75 * vlt) + cur;
        spk = (vlt > 0.5) ? 1 : 0;
        out[(size_t)t * 65536 + n] = (unsigned char)spk;
    }
}

// ---------------- temporal-conv PSP (3-tap over s3 history), fp64 ----------------
__global__ __launch_bounds__(256) void k_tcpsp(const unsigned char* __restrict__ s3,
        const double* __restrict__ tcwt, const float* __restrict__ tcb,
        double* __restrict__ psp) {
    __shared__ __align__(16) float sv[8 * 768];
    int t  = blockIdx.x >> 5;
    int bg = blockIdx.x & 31;
    int oc = threadIdx.x;
    for (int i = threadIdx.x; i < 8 * 768; i += 256) {
        int bb = i / 768, kk = i - bb * 768;
        int j = kk >> 8, k = kk & 255;
        int src = (t >= 2) ? (t - 2 + j) : ((j <= t) ? j : -1);  // j-th OLDEST
        float v = 0.f;
        if (src >= 0) v = (float)s3[((size_t)src * B + bg * 8 + bb) * 256 + k];
        sv[i] = v;
    }
    double bias = (double)tcb[oc];
    if (t >= 1) bias += (double)tcb[256 + oc];
    if (t >= 2) bias += (double)tcb[512 + oc];
    __syncthreads();
    double z[8];
#pragma unroll
    for (int j = 0; j < 8; ++j) z[j] = bias;
    for (int k = 0; k < 768; k += 4) {
        double w0 = tcwt[(k + 0) * 256 + oc];
        double w1 = tcwt[(k + 1) * 256 + oc];
        double w2 = tcwt[(k + 2) * 256 + oc];
        double w3 = tcwt[(k + 3) * 256 + oc];
#pragma unroll
        for (int j = 0; j < 8; ++j) {
            float4 a = *(const float4*)&sv[j * 768 + k];
            z[j] = fma(w0, (double)a.x, z[j]); z[j] = fma(w1, (double)a.y, z[j]);
            z[j] = fma(w2, (double)a.z, z[j]); z[j] = fma(w3, (double)a.w, z[j]);
        }
    }
    double* out = psp + (size_t)(t * B + bg * 8) * 256 + oc;
#pragma unroll
    for (int j = 0; j < 8; ++j) out[j * 256] = z[j];
}

// ---------------- recurrent layer: per-sample block, t-sequential, sparse-skip ---
__global__ __launch_bounds__(256) void k_rec(const unsigned char* __restrict__ tcspk,
        const double* __restrict__ recwt, const float* __restrict__ rb,
        unsigned char* __restrict__ rspk) {
    __shared__ __align__(16) float rs[256];
    int b = blockIdx.x, oc = threadIdx.x;
    rs[oc] = 0.f;
    double bias = (double)rb[oc];
    double cur = 0.0, vlt = 0.0;
    int spk = 0;
    __syncthreads();
    for (int t = 0; t < T; ++t) {
        double z = bias + (double)tcspk[((size_t)t * B + b) * 256 + oc];
        for (int k = 0; k < 256; k += 4) {
            float4 s4 = *(const float4*)&rs[k];
            if (__builtin_amdgcn_readfirstlane(__float_as_int(s4.x))) z += recwt[(k + 0) * 256 + oc];
            if (__builtin_amdgcn_readfirstlane(__float_as_int(s4.y))) z += recwt[(k + 1) * 256 + oc];
            if (__builtin_amdgcn_readfirstlane(__float_as_int(s4.z))) z += recwt[(k + 2) * 256 + oc];
            if (__builtin_amdgcn_readfirstlane(__float_as_int(s4.w))) z += recwt[(k + 3) * 256 + oc];
        }
        cur = 0.5 * cur + z;
        vlt = (spk ? 0.0 : 0.75 * vlt) + cur;
        spk = (vlt > 0.5) ? 1 : 0;
        rspk[((size_t)t * B + b) * 256 + oc] = (unsigned char)spk;
        __syncthreads();
        rs[oc] = (float)spk;
        __syncthreads();
    }
}

// ---------------- fc1 + LIF + fc2 accumulate -> d_out, fp64 ----------------
__global__ __launch_bounds__(128) void k_fc(const unsigned char* __restrict__ rspk,
        const double* __restrict__ fc1wt, const float* __restrict__ f1b,
        const float* __restrict__ fc2w, const float* __restrict__ tsw,
        float* __restrict__ out) {
    __shared__ __align__(16) float rv[256];
    __shared__ float f1buf[128];
    int b = blockIdx.x, oc = threadIdx.x;
    double bias = (double)f1b[oc];
    double cur = 0.0, vlt = 0.0, acc = 0.0;
    int spk = 0;
    for (int t = 0; t < T; ++t) {
        const unsigned char* rp = rspk + ((size_t)t * B + b) * 256;
        rv[oc]       = (float)rp[oc];
        rv[oc + 128] = (float)rp[oc + 128];
        __syncthreads();
        double z = bias;
        for (int k = 0; k < 256; k += 4) {
            float4 s4 = *(const float4*)&rv[k];
            if (__builtin_amdgcn_readfirstlane(__float_as_int(s4.x))) z += fc1wt[(k + 0) * 128 + oc];
            if (__builtin_amdgcn_readfirstlane(__float_as_int(s4.y))) z += fc1wt[(k + 1) * 128 + oc];
            if (__builtin_amdgcn_readfirstlane(__float_as_int(s4.z))) z += fc1wt[(k + 2) * 128 + oc];
            if (__builtin_amdgcn_readfirstlane(__float_as_int(s4.w))) z += fc1wt[(k + 3) * 128 + oc];
        }
        cur = 0.5 * cur + z;
        vlt = (spk ? 0.0 : 0.75 * vlt) + cur;
        spk = (vlt > 0.5) ? 1 : 0;
        f1buf[oc] = (float)spk;
        __syncthreads();
        if (oc < 2) {
            double s = 0.0;
            for (int k = 0; k < 128; ++k)
                s = fma((double)f1buf[k], (double)fc2w[oc * 128 + k], s);
            acc = fma(s, (double)tsw[t], acc);
        }
        __syncthreads();
    }
    if (oc < 2) out[b * 2 + oc] = (float)acc;
}

extern "C" void kernel_launch(void* const* d_in, const int* in_sizes, int n_in,
                              void* d_out, int out_size, void* d_ws, size_t ws_size,
                              hipStream_t stream) {
    const float* x   = (const float*)d_in[0];
    const float* c1w = (const float*)d_in[1];
    const float* c1b = (const float*)d_in[2];
    const float* c2w = (const float*)d_in[3];
    const float* c2b = (const float*)d_in[4];
    const float* c3w = (const float*)d_in[5];
    const float* c3b = (const float*)d_in[6];
    const float* tcw = (const float*)d_in[7];
    const float* tcb = (const float*)d_in[8];
    const float* rcw = (const float*)d_in[9];
    const float* rcb = (const float*)d_in[10];
    const float* f1w = (const float*)d_in[11];
    const float* f1b = (const float*)d_in[12];
    const float* f2w = (const float*)d_in[13];
    const float* tsw = (const float*)d_in[14];

    char* ws = (char*)d_ws;
    signed char* Bd       = (signed char*)(ws + OFF_BD);
    double* w3t           = (double*)(ws + OFF_W3T);
    double* tcwt          = (double*)(ws + OFF_TCWT);
    double* recwt         = (double*)(ws + OFF_RECWT);
    double* fc1wt         = (double*)(ws + OFF_FC1WT);
    unsigned char* s1     = (unsigned char*)(ws + OFF_S1);
    unsigned char* pool   = (unsigned char*)(ws + OFF_POOL);
    double* psp3          = (double*)(ws + OFF_PSP3);
    unsigned char* s3     = (unsigned char*)(ws + OFF_S3);
    double* psptc         = (double*)(ws + OFF_PSPTC);
    unsigned char* tcs    = (unsigned char*)(ws + OFF_TC);
    unsigned char* rsp    = (unsigned char*)(ws + OFF_R);

    k_prep    <<<2304, 256, 0, stream>>>(c3w, tcw, rcw, f1w, w3t, tcwt, recwt, fc1wt);
    k_prep2   <<<288,  256, 0, stream>>>(c2w, Bd);
    k_conv1   <<<256,  256, 0, stream>>>(x, c1w, c1b, s1);
    k_conv2   <<<2304, 256, 0, stream>>>(s1, Bd, c2b, pool);
    k_c3psp   <<<1024, 256, 0, stream>>>(pool, w3t, c3b, psp3);
    k_lif_flat<<<256,  256, 0, stream>>>(psp3, s3);
    k_tcpsp   <<<1024, 256, 0, stream>>>(s3, tcwt, tcb, psptc);
    k_lif_flat<<<256,  256, 0, stream>>>(psptc, tcs);
    k_rec     <<<256,  256, 0, stream>>>(tcs, recwt, rcb, rsp);
    k_fc      <<<256,  128, 0, stream>>>(rsp, fc1wt, f1b, f2w, tsw, (float*)d_out);
}

// Round 4
// 982.707 us; speedup vs baseline: 3.1752x; 2.2748x over previous
//
#include <hip/hip_runtime.h>

#define T 32
#define B 256

typedef int v4i __attribute__((ext_vector_type(4)));

// ---------------- workspace byte offsets ----------------
#define OFF_BD    0            // int8  [5][128][576] conv2 weight digits   368,640
#define OFF_W3T   368640       // double [1152][256]                      2,359,296
#define OFF_TCWT  2727936      // double [768][256]                       1,572,864
#define OFF_RECWT 4300800      // double [256][256]                         524,288
#define OFF_FC1WT 4825088      // double [256][128]                         262,144
#define OFF_S1    5087232      // uchar [T][B][pix 64][ic 64]            33,554,432
#define OFF_POOL  38641664     // uchar [T][B][128][9]                    9,437,184
#define OFF_PSP3  48078848     // double [T][B][256]                     16,777,216
#define OFF_S3    64856064     // uchar [T][B][256]                       2,097,152
#define OFF_PSPTC 66953216     // double [T][B][256]                     16,777,216
#define OFF_TC    83730432     // uchar [T][B][256]                       2,097,152
#define OFF_R     85827584     // uchar [T][B][256]                       2,097,152
#define OFF_PSPF1 OFF_PSPTC    // double [T][B][128] — reuses psptc (retired before k_rec)
// total 87,924,736 bytes

// ---------------- fp64 weight transposes (c3 / tc / rec / fc1) ----------------
__global__ __launch_bounds__(256) void k_prep(const float* __restrict__ c3w,
        const float* __restrict__ tcw, const float* __restrict__ rcw,
        const float* __restrict__ f1w, double* __restrict__ w3t,
        double* __restrict__ tcwt, double* __restrict__ recwt,
        double* __restrict__ fc1wt) {
    int n = blockIdx.x * 256 + threadIdx.x;
    if (n < 294912) {                      // w3t[k][oc] <- conv3_w[oc][ic][3][3]
        int oc = n & 255, k = n >> 8;
        w3t[n] = (double)c3w[(oc * 128 + k / 9) * 9 + k % 9];
    } else if (n < 491520) {               // tcwt[j*256+k][oc] <- tc_w[j][oc][k]
        int m = n - 294912;
        int oc = m & 255, kp = m >> 8;
        int j = kp >> 8, k = kp & 255;
        tcwt[m] = (double)tcw[(j * 256 + oc) * 256 + k];
    } else if (n < 557056) {               // recwt[k][oc] <- rec_w[oc][k]
        int m = n - 491520;
        int oc = m & 255, k = m >> 8;
        recwt[m] = (double)rcw[oc * 256 + k];
    } else if (n < 589824) {               // fc1wt[k][oc] <- fc1_w[oc][k]
        int m = n - 557056;
        int oc = m & 127, k = m >> 7;
        fc1wt[m] = (double)f1w[oc * 256 + k];
    }
}

// ---------------- conv2 weight digit decomposition -----------------------------
__global__ __launch_bounds__(256) void k_prep2(const float* __restrict__ c2w,
        signed char* __restrict__ Bd) {
    int idx = blockIdx.x * 256 + threadIdx.x;      // 73728 = 128 oc * 576 k
    if (idx >= 73728) return;
    int oc = idx / 576, kpos = idx - oc * 576;
    int kk = kpos >> 6, ic = kpos & 63;
    int ky = kk / 3, kx = kk - ky * 3;
    float w = c2w[((oc * 64 + ic) * 3 + ky) * 3 + kx];
    long long W = (long long)rint((double)w * 274877906944.0);   // 2^38
#pragma unroll
    for (int d = 0; d < 4; ++d) {
        int dig = (int)(((W + 128) & 255) - 128);
        Bd[d * 73728 + idx] = (signed char)dig;
        W = (W - dig) >> 8;
    }
    Bd[4 * 73728 + idx] = (signed char)W;
}

// ---------------- conv1 + LIF1 -> s1 [t][b][pix][ic], fp64 state ----------------
__global__ __launch_bounds__(256) void k_conv1(const float* __restrict__ x,
        const float* __restrict__ w1, const float* __restrict__ b1,
        unsigned char* __restrict__ s1) {
    __shared__ float xl[3200];
    int b  = blockIdx.x;
    int oc = threadIdx.x & 63;
    int pg = threadIdx.x >> 6;              // 0..3
    const float* xb = x + b * 3200;         // input_data[b][0][10][10][T], t innermost
    for (int i = threadIdx.x; i < 3200; i += 256)
        xl[(i & 31) * 100 + (i >> 5)] = xb[i];   // LDS [t][pos]
    double wd[9];
#pragma unroll
    for (int j = 0; j < 9; ++j) wd[j] = (double)w1[oc * 9 + j];
    double bias = (double)b1[oc];
    __syncthreads();
    double cur[16], vlt[16];
    unsigned spkb = 0;
#pragma unroll
    for (int i = 0; i < 16; ++i) { cur[i] = 0.0; vlt[i] = 0.0; }
    for (int t = 0; t < T; ++t) {
#pragma unroll
        for (int i = 0; i < 16; ++i) {
            int pix = pg * 16 + i;
            int oy = pix >> 3, ox = pix & 7;
            const float* xt = &xl[t * 100 + oy * 10 + ox];
            double z = bias;
#pragma unroll
            for (int ky = 0; ky < 3; ++ky)
#pragma unroll
                for (int kx = 0; kx < 3; ++kx)
                    z = fma(wd[ky * 3 + kx], (double)xt[ky * 10 + kx], z);
            cur[i] = 0.5 * cur[i] + z;
            int s = (spkb >> i) & 1;
            vlt[i] = (s ? 0.0 : 0.75 * vlt[i]) + cur[i];
            s = (vlt[i] > 0.5) ? 1 : 0;
            spkb = (spkb & ~(1u << i)) | ((unsigned)s << i);
            s1[((size_t)(t * B + b) * 64 + pix) * 64 + oc] = (unsigned char)s;
        }
    }
}

// ---------------- conv2 via exact i8-digit MFMA + in-block LIF + avgpool --------
__global__ __launch_bounds__(256) void k_conv2(const unsigned char* __restrict__ s1,
        const signed char* __restrict__ Bd, const float* __restrict__ cb2,
        unsigned char* __restrict__ pooled) {
    __shared__ double pl[2][4][4][64];
    __shared__ unsigned smask[4][64];
    const int b    = blockIdx.x / 9;
    const int w    = blockIdx.x - b * 9;
    const int wy   = w / 3, wx = w - wy * 3;
    const int wave = threadIdx.x >> 6, lane = threadIdx.x & 63;
    const int col  = lane & 15, quad = lane >> 4;
    const int tq   = (lane & 15) >> 2;
    const int apx  = lane & 3;
    const int apy  = apx >> 1, apxx = apx & 1;
    const int oc_l = threadIdx.x & 63;
    const int px_e = threadIdx.x >> 6;
    const unsigned char* s1b = s1 + (size_t)b * 4096;
    const double scl[5] = { 0x1p-38, 0x1p-30, 0x1p-22, 0x1p-14, 0x1p-6 };

    for (int nh = 0; nh < 2; ++nh) {
        const int ocb = nh * 64 + wave * 16;
        const signed char* Bw = Bd + (size_t)(ocb + col) * 576 + quad * 16;
        double cur = 0.0, vlt = 0.0;
        int spk = 0;
        unsigned bits = 0;
        double bias = (double)cb2[nh * 64 + oc_l];

        for (int mp = 0; mp < 4; ++mp) {
            v4i acc[5][2];
#pragma unroll
            for (int d = 0; d < 5; ++d) {
                acc[d][0] = (v4i){0, 0, 0, 0};
                acc[d][1] = (v4i){0, 0, 0, 0};
            }
#pragma unroll
            for (int ky = 0; ky < 3; ++ky) {
#pragma unroll
                for (int kx = 0; kx < 3; ++kx) {
                    const int kk = ky * 3 + kx;
                    const int pix = (2 * wy + apy + ky) * 8 + (2 * wx + apxx + kx);
                    v4i Af[2];
#pragma unroll
                    for (int j = 0; j < 2; ++j) {
                        int t = (2 * mp + j) * 4 + tq;
                        Af[j] = *(const v4i*)(s1b + (size_t)t * (B * 4096) + pix * 64 + quad * 16);
                    }
#pragma unroll
                    for (int d = 0; d < 5; ++d) {
                        v4i Bf = *(const v4i*)(Bw + d * 73728 + kk * 64);
                        acc[d][0] = __builtin_amdgcn_mfma_i32_16x16x64_i8(Af[0], Bf, acc[d][0], 0, 0, 0);
                        acc[d][1] = __builtin_amdgcn_mfma_i32_16x16x64_i8(Af[1], Bf, acc[d][1], 0, 0, 0);
                    }
                }
            }
            __syncthreads();
#pragma unroll
            for (int j = 0; j < 2; ++j)
#pragma unroll
                for (int r = 0; r < 4; ++r) {
                    double p = 0.0;
#pragma unroll
                    for (int d = 0; d < 5; ++d)
                        p = fma((double)acc[d][j][r], scl[d], p);
                    pl[j][quad][r][wave * 16 + col] = p;
                }
            __syncthreads();
#pragma unroll
            for (int j = 0; j < 2; ++j)
#pragma unroll
                for (int q = 0; q < 4; ++q) {
                    int t = (2 * mp + j) * 4 + q;
                    double z = bias + pl[j][q][px_e][oc_l];
                    cur = 0.5 * cur + z;
                    vlt = (spk ? 0.0 : 0.75 * vlt) + cur;
                    spk = (vlt > 0.5) ? 1 : 0;
                    bits |= ((unsigned)spk) << t;
                }
        }
        smask[px_e][oc_l] = bits;
        __syncthreads();
        if (px_e == 0) {
            unsigned m0 = smask[0][oc_l], m1 = smask[1][oc_l];
            unsigned m2 = smask[2][oc_l], m3 = smask[3][oc_l];
            int ocg = nh * 64 + oc_l;
            for (int t = 0; t < T; ++t) {
                unsigned s = ((m0 >> t) & 1) + ((m1 >> t) & 1) + ((m2 >> t) & 1) + ((m3 >> t) & 1);
                pooled[((size_t)(t * B + b) * 128 + ocg) * 9 + w] = (unsigned char)s;
            }
        }
        __syncthreads();
    }
}

// ---------------- conv3 PSP: fp64 GEMM over all (t,b) rows ----------------
__global__ __launch_bounds__(256) void k_c3psp(const unsigned char* __restrict__ pooled,
        const double* __restrict__ w3t, const float* __restrict__ b3,
        double* __restrict__ psp) {
    __shared__ __align__(16) float ap[8 * 1152];
    int t  = blockIdx.x >> 5;
    int bg = blockIdx.x & 31;
    int oc = threadIdx.x;
    const unsigned char* src = pooled + (size_t)(t * B + bg * 8) * 1152;
    for (int i = threadIdx.x; i < 8 * 1152; i += 256)
        ap[i] = 0.25f * (float)src[i];
    __syncthreads();
    double bias = (double)b3[oc];
    double z[8];
#pragma unroll
    for (int j = 0; j < 8; ++j) z[j] = bias;
    for (int k = 0; k < 1152; k += 4) {
        double w0 = w3t[(k + 0) * 256 + oc];
        double w1 = w3t[(k + 1) * 256 + oc];
        double w2 = w3t[(k + 2) * 256 + oc];
        double w3 = w3t[(k + 3) * 256 + oc];
#pragma unroll
        for (int j = 0; j < 8; ++j) {
            float4 a = *(const float4*)&ap[j * 1152 + k];
            z[j] = fma(w0, (double)a.x, z[j]); z[j] = fma(w1, (double)a.y, z[j]);
            z[j] = fma(w2, (double)a.z, z[j]); z[j] = fma(w3, (double)a.w, z[j]);
        }
    }
    double* out = psp + (size_t)(t * B + bg * 8) * 256 + oc;
#pragma unroll
    for (int j = 0; j < 8; ++j) out[j * 256] = z[j];
}

// ---------------- sequential LIF sweep over [T][B*256] fp64 psp -> spikes -------
__global__ __launch_bounds__(256) void k_lif_flat(const double* __restrict__ psp,
        unsigned char* __restrict__ out) {
    int n = blockIdx.x * 256 + threadIdx.x;
    double cur = 0.0, vlt = 0.0;
    int spk = 0;
    for (int t = 0; t < T; ++t) {
        double z = psp[(size_t)t * 65536 + n];
        cur = 0.5 * cur + z;
        vlt = (spk ? 0.0 : 0.75 * vlt) + cur;
        spk = (vlt > 0.5) ? 1 : 0;
        out[(size_t)t * 65536 + n] = (unsigned char)spk;
    }
}

// ---------------- temporal-conv PSP (3-tap over s3 history), fp64 ----------------
__global__ __launch_bounds__(256) void k_tcpsp(const unsigned char* __restrict__ s3,
        const double* __restrict__ tcwt, const float* __restrict__ tcb,
        double* __restrict__ psp) {
    __shared__ __align__(16) float sv[8 * 768];
    int t  = blockIdx.x >> 5;
    int bg = blockIdx.x & 31;
    int oc = threadIdx.x;
    for (int i = threadIdx.x; i < 8 * 768; i += 256) {
        int bb = i / 768, kk = i - bb * 768;
        int j = kk >> 8, k = kk & 255;
        int src = (t >= 2) ? (t - 2 + j) : ((j <= t) ? j : -1);  // j-th OLDEST
        float v = 0.f;
        if (src >= 0) v = (float)s3[((size_t)src * B + bg * 8 + bb) * 256 + k];
        sv[i] = v;
    }
    double bias = (double)tcb[oc];
    if (t >= 1) bias += (double)tcb[256 + oc];
    if (t >= 2) bias += (double)tcb[512 + oc];
    __syncthreads();
    double z[8];
#pragma unroll
    for (int j = 0; j < 8; ++j) z[j] = bias;
    for (int k = 0; k < 768; k += 4) {
        double w0 = tcwt[(k + 0) * 256 + oc];
        double w1 = tcwt[(k + 1) * 256 + oc];
        double w2 = tcwt[(k + 2) * 256 + oc];
        double w3 = tcwt[(k + 3) * 256 + oc];
#pragma unroll
        for (int j = 0; j < 8; ++j) {
            float4 a = *(const float4*)&sv[j * 768 + k];
            z[j] = fma(w0, (double)a.x, z[j]); z[j] = fma(w1, (double)a.y, z[j]);
            z[j] = fma(w2, (double)a.z, z[j]); z[j] = fma(w3, (double)a.w, z[j]);
        }
    }
    double* out = psp + (size_t)(t * B + bg * 8) * 256 + oc;
#pragma unroll
    for (int j = 0; j < 8; ++j) out[j * 256] = z[j];
}

// ---------------- recurrent layer: dense fp64 matvec, weights in registers ------
// grid 256 (b) ; block 1024 = 4 k-slices x 256 oc ; per t: 64 FMA + LDS reduce
__global__ __launch_bounds__(1024) void k_rec(const unsigned char* __restrict__ tcspk,
        const double* __restrict__ recwt, const float* __restrict__ rb,
        unsigned char* __restrict__ rspk) {
    __shared__ double rs[256];              // spike vector (as double)
    __shared__ double partial[4][256];
    int b  = blockIdx.x;
    int oc = threadIdx.x & 255;
    int ks = threadIdx.x >> 8;              // 0..3
    double wreg[64];
#pragma unroll
    for (int i = 0; i < 64; ++i)
        wreg[i] = recwt[(size_t)(ks * 64 + i) * 256 + oc];   // coalesced along oc
    if (ks == 0) rs[oc] = 0.0;
    double bias = (double)rb[oc];
    double cur = 0.0, vlt = 0.0;
    int spk = 0;
    __syncthreads();
    for (int t = 0; t < T; ++t) {
        const double* rsk = &rs[ks * 64];
        double z0 = 0.0, z1 = 0.0;
#pragma unroll
        for (int i = 0; i < 64; i += 2) {   // LDS broadcast reads (wave-uniform addr)
            z0 = fma(wreg[i],     rsk[i],     z0);
            z1 = fma(wreg[i + 1], rsk[i + 1], z1);
        }
        partial[ks][oc] = z0 + z1;
        __syncthreads();
        if (ks == 0) {
            double z = bias + (double)tcspk[((size_t)t * B + b) * 256 + oc]
                     + ((partial[0][oc] + partial[1][oc]) + (partial[2][oc] + partial[3][oc]));
            cur = 0.5 * cur + z;
            vlt = (spk ? 0.0 : 0.75 * vlt) + cur;
            spk = (vlt > 0.5) ? 1 : 0;
            rspk[((size_t)t * B + b) * 256 + oc] = (unsigned char)spk;
            rs[oc] = (double)spk;
        }
        __syncthreads();
    }
}

// ---------------- fc1 PSP: fp64 GEMM over all (t,b) rows ----------------
// grid 1024 = 32 t * 32 bg(8) ; block 128 (oc) ; K = 256
__global__ __launch_bounds__(128) void k_f1psp(const unsigned char* __restrict__ rspk,
        const double* __restrict__ fc1wt, const float* __restrict__ f1b,
        double* __restrict__ psp) {
    __shared__ __align__(16) float rv[8 * 256];
    int t  = blockIdx.x >> 5;
    int bg = blockIdx.x & 31;
    int oc = threadIdx.x;
    const unsigned char* src = rspk + (size_t)(t * B + bg * 8) * 256;
    for (int i = threadIdx.x; i < 8 * 256; i += 128)
        rv[i] = (float)src[i];
    __syncthreads();
    double bias = (double)f1b[oc];
    double z[8];
#pragma unroll
    for (int j = 0; j < 8; ++j) z[j] = bias;
    for (int k = 0; k < 256; k += 4) {
        double w0 = fc1wt[(k + 0) * 128 + oc];
        double w1 = fc1wt[(k + 1) * 128 + oc];
        double w2 = fc1wt[(k + 2) * 128 + oc];
        double w3 = fc1wt[(k + 3) * 128 + oc];
#pragma unroll
        for (int j = 0; j < 8; ++j) {
            float4 a = *(const float4*)&rv[j * 256 + k];
            z[j] = fma(w0, (double)a.x, z[j]); z[j] = fma(w1, (double)a.y, z[j]);
            z[j] = fma(w2, (double)a.z, z[j]); z[j] = fma(w3, (double)a.w, z[j]);
        }
    }
    double* out = psp + (size_t)(t * B + bg * 8) * 128 + oc;
#pragma unroll
    for (int j = 0; j < 8; ++j) out[j * 128] = z[j];
}

// ---------------- fc1 LIF (registers) + fc2 via end-of-time reduction ----------
// out[b][o] = sum_k fc2w[o][k] * (sum_t tsw[t] * f1spk[t][k])
__global__ __launch_bounds__(128) void k_fc_out(const double* __restrict__ psp,
        const float* __restrict__ fc2w, const float* __restrict__ tsw,
        float* __restrict__ out) {
    __shared__ double sm[128];
    int b = blockIdx.x, oc = threadIdx.x;
    double ps[T];
#pragma unroll
    for (int t = 0; t < T; ++t)
        ps[t] = psp[((size_t)t * B + b) * 128 + oc];
    double cur = 0.0, vlt = 0.0, sAcc = 0.0;
    int spk = 0;
#pragma unroll
    for (int t = 0; t < T; ++t) {
        cur = 0.5 * cur + ps[t];
        vlt = (spk ? 0.0 : 0.75 * vlt) + cur;
        spk = (vlt > 0.5) ? 1 : 0;
        if (spk) sAcc += (double)tsw[t];
    }
    sm[oc] = sAcc;
    __syncthreads();
    if (oc < 2) {
        double s = 0.0;
        for (int k = 0; k < 128; ++k)
            s = fma(sm[k], (double)fc2w[oc * 128 + k], s);
        out[b * 2 + oc] = (float)s;
    }
}

extern "C" void kernel_launch(void* const* d_in, const int* in_sizes, int n_in,
                              void* d_out, int out_size, void* d_ws, size_t ws_size,
                              hipStream_t stream) {
    const float* x   = (const float*)d_in[0];
    const float* c1w = (const float*)d_in[1];
    const float* c1b = (const float*)d_in[2];
    const float* c2w = (const float*)d_in[3];
    const float* c2b = (const float*)d_in[4];
    const float* c3w = (const float*)d_in[5];
    const float* c3b = (const float*)d_in[6];
    const float* tcw = (const float*)d_in[7];
    const float* tcb = (const float*)d_in[8];
    const float* rcw = (const float*)d_in[9];
    const float* rcb = (const float*)d_in[10];
    const float* f1w = (const float*)d_in[11];
    const float* f1b = (const float*)d_in[12];
    const float* f2w = (const float*)d_in[13];
    const float* tsw = (const float*)d_in[14];

    char* ws = (char*)d_ws;
    signed char* Bd       = (signed char*)(ws + OFF_BD);
    double* w3t           = (double*)(ws + OFF_W3T);
    double* tcwt          = (double*)(ws + OFF_TCWT);
    double* recwt         = (double*)(ws + OFF_RECWT);
    double* fc1wt         = (double*)(ws + OFF_FC1WT);
    unsigned char* s1     = (unsigned char*)(ws + OFF_S1);
    unsigned char* pool   = (unsigned char*)(ws + OFF_POOL);
    double* psp3          = (double*)(ws + OFF_PSP3);
    unsigned char* s3     = (unsigned char*)(ws + OFF_S3);
    double* psptc         = (double*)(ws + OFF_PSPTC);
    unsigned char* tcs    = (unsigned char*)(ws + OFF_TC);
    unsigned char* rsp    = (unsigned char*)(ws + OFF_R);
    double* pspf1         = (double*)(ws + OFF_PSPF1);   // aliases psptc (retired)

    k_prep    <<<2304, 256, 0, stream>>>(c3w, tcw, rcw, f1w, w3t, tcwt, recwt, fc1wt);
    k_prep2   <<<288,  256, 0, stream>>>(c2w, Bd);
    k_conv1   <<<256,  256, 0, stream>>>(x, c1w, c1b, s1);
    k_conv2   <<<2304, 256, 0, stream>>>(s1, Bd, c2b, pool);
    k_c3psp   <<<1024, 256, 0, stream>>>(pool, w3t, c3b, psp3);
    k_lif_flat<<<256,  256, 0, stream>>>(psp3, s3);
    k_tcpsp   <<<1024, 256, 0, stream>>>(s3, tcwt, tcb, psptc);
    k_lif_flat<<<256,  256, 0, stream>>>(psptc, tcs);
    k_rec     <<<256, 1024, 0, stream>>>(tcs, recwt, rcb, rsp);
    k_f1psp   <<<1024, 128, 0, stream>>>(rsp, fc1wt, f1b, pspf1);
    k_fc_out  <<<256,  128, 0, stream>>>(pspf1, f2w, tsw, (float*)d_out);
}

// Round 5
// 685.233 us; speedup vs baseline: 4.5536x; 1.4341x over previous
//
#include <hip/hip_runtime.h>

#define T 32
#define B 256

typedef int v4i __attribute__((ext_vector_type(4)));

// ---------------- workspace byte offsets ----------------
#define OFF_BD2   0            // int8 [5][128][576]   conv2 digits      368,640
#define OFF_BD3   368640       // int8 [5][256][1152]  conv3 digits    1,474,560
#define OFF_BDTC  1843200      // int8 [5][256][768]   tc digits         983,040
#define OFF_BDF1  2826240      // int8 [5][128][256]   fc1 digits        163,840
#define OFF_RECWT 2990080      // double [256][256]                      524,288
#define OFF_S1    3514368      // uchar [T][B][pix64][ic64]           33,554,432
#define OFF_POOL  37068800     // uchar [w9][t32][b256][oc128]         9,437,184
#define OFF_PSP3  46505984     // double [8192][256]                  16,777,216
#define OFF_S3    63283200     // uchar [t][b][256]                    2,097,152
#define OFF_PSPTC 65380352     // double [8192][256]                  16,777,216
#define OFF_TC    82157568     // uchar [t][b][256]                    2,097,152
#define OFF_R     84254720     // uchar [t][b][256]                    2,097,152
#define OFF_PSPF1 OFF_PSPTC    // double [8192][128] — reuses psptc (retired)
// total 86,351,872 bytes

// ---------------- rec weight transpose (fp64) ----------------
__global__ __launch_bounds__(256) void k_prep(const float* __restrict__ rcw,
        double* __restrict__ recwt) {
    int n = blockIdx.x * 256 + threadIdx.x;        // k*256+oc
    int oc = n & 255, k = n >> 8;
    recwt[n] = (double)rcw[oc * 256 + k];
}

// ---------------- weight digit decomposition (all i8-GEMM layers) ----------------
// W = rint(w*2^38), 5 signed base-256 digits; layouts: Bd[d][oc][k]
__global__ __launch_bounds__(256) void k_prepd(const float* __restrict__ c2w,
        const float* __restrict__ c3w, const float* __restrict__ tcw,
        const float* __restrict__ f1w, signed char* __restrict__ Bd2,
        signed char* __restrict__ Bd3, signed char* __restrict__ Bdtc,
        signed char* __restrict__ Bdf1) {
    int idx = blockIdx.x * 256 + threadIdx.x;
    float w; signed char* base; int plane, off;
    if (idx < 73728) {                       // conv2: k=(ky*3+kx)*64+ic
        int oc = idx / 576, kpos = idx - oc * 576;
        int kk = kpos >> 6, ic = kpos & 63;
        int ky = kk / 3, kx = kk - ky * 3;
        w = c2w[((oc * 64 + ic) * 3 + ky) * 3 + kx];
        base = Bd2; plane = 73728; off = idx;
    } else if (idx < 368640) {               // conv3: k = win*128+ic
        int m = idx - 73728;
        int oc = m / 1152, kpos = m - oc * 1152;
        int win = kpos >> 7, ic = kpos & 127;
        w = c3w[(oc * 128 + ic) * 9 + win];
        base = Bd3; plane = 294912; off = m;
    } else if (idx < 565248) {               // tc: k = j*256+kc (j = oldest-first tap)
        int m = idx - 368640;
        int oc = m / 768, kpos = m - oc * 768;
        int j = kpos >> 8, kc = kpos & 255;
        w = tcw[(j * 256 + oc) * 256 + kc];
        base = Bdtc; plane = 196608; off = m;
    } else if (idx < 598016) {               // fc1: k = kc
        int m = idx - 565248;
        int oc = m >> 8, kc = m & 255;
        w = f1w[oc * 256 + kc];
        base = Bdf1; plane = 32768; off = m;
    } else return;
    long long W = (long long)rint((double)w * 274877906944.0);   // 2^38
#pragma unroll
    for (int d = 0; d < 4; ++d) {
        int dig = (int)(((W + 128) & 255) - 128);
        base[d * plane + off] = (signed char)dig;
        W = (W - dig) >> 8;
    }
    base[4 * plane + off] = (signed char)W;
}

// ---------------- conv1 + LIF1 -> s1 [t][b][pix][ic], fp64 state ----------------
__global__ __launch_bounds__(256) void k_conv1(const float* __restrict__ x,
        const float* __restrict__ w1, const float* __restrict__ b1,
        unsigned char* __restrict__ s1) {
    __shared__ float xl[3200];
    int b  = blockIdx.x;
    int oc = threadIdx.x & 63;
    int pg = threadIdx.x >> 6;              // 0..3
    const float* xb = x + b * 3200;         // input_data[b][0][10][10][T], t innermost
    for (int i = threadIdx.x; i < 3200; i += 256)
        xl[(i & 31) * 100 + (i >> 5)] = xb[i];   // LDS [t][pos]
    double wd[9];
#pragma unroll
    for (int j = 0; j < 9; ++j) wd[j] = (double)w1[oc * 9 + j];
    double bias = (double)b1[oc];
    __syncthreads();
    double cur[16], vlt[16];
    unsigned spkb = 0;
#pragma unroll
    for (int i = 0; i < 16; ++i) { cur[i] = 0.0; vlt[i] = 0.0; }
    for (int t = 0; t < T; ++t) {
#pragma unroll
        for (int i = 0; i < 16; ++i) {
            int pix = pg * 16 + i;
            int oy = pix >> 3, ox = pix & 7;
            const float* xt = &xl[t * 100 + oy * 10 + ox];
            double z = bias;
#pragma unroll
            for (int ky = 0; ky < 3; ++ky)
#pragma unroll
                for (int kx = 0; kx < 3; ++kx)
                    z = fma(wd[ky * 3 + kx], (double)xt[ky * 10 + kx], z);
            cur[i] = 0.5 * cur[i] + z;
            int s = (spkb >> i) & 1;
            vlt[i] = (s ? 0.0 : 0.75 * vlt[i]) + cur[i];
            s = (vlt[i] > 0.5) ? 1 : 0;
            spkb = (spkb & ~(1u << i)) | ((unsigned)s << i);
            s1[((size_t)(t * B + b) * 64 + pix) * 64 + oc] = (unsigned char)s;
        }
    }
}

// ---------------- conv2: A-in-LDS i8-digit MFMA + in-block LIF + avgpool --------
// grid B*9 ; block 256. A (16 win pixels x 32 t x 64 ic) staged once, shared by
// 4 waves x 2 nh. B digits stay in L2. pooled layout [w][t][b][oc] (coalesced).
__global__ __launch_bounds__(256, 4) void k_conv2(const unsigned char* __restrict__ s1,
        const signed char* __restrict__ Bd2, const float* __restrict__ cb2,
        unsigned char* __restrict__ pooled) {
    __shared__ __align__(16) unsigned char As[32 * 1040];  // [t][p16][ic64], pad 16
    __shared__ double pl[2][4][4][64];
    __shared__ unsigned smask[4][64];
    const int b = blockIdx.x / 9;
    const int w = blockIdx.x - b * 9;
    const int wy = w / 3, wx = w - wy * 3;
    const int tid = threadIdx.x;
    const int wave = tid >> 6, lane = tid & 63;
    const int col = lane & 15, quad = lane >> 4;
    const int m = lane & 15;
    const int tq = m >> 2, apx = m & 3;
    const int apy = apx >> 1, apxx = apx & 1;
    const int oc_l = tid & 63, px_e = tid >> 6;
    const double scl[5] = { 0x1p-38, 0x1p-30, 0x1p-22, 0x1p-14, 0x1p-6 };

    {   // stage A
        const int pixbase = (2 * wy) * 8 + 2 * wx;
        for (int c = tid; c < 2048; c += 256) {
            int t = c >> 6, rem = c & 63;
            int p = rem >> 2, qo = rem & 3;
            int ly = p >> 2, lx = p & 3;
            int pix = pixbase + ly * 8 + lx;
            v4i v = *(const v4i*)(s1 + (((size_t)(t * B + b) * 64 + pix) << 6) + qo * 16);
            *(v4i*)(As + t * 1040 + p * 64 + qo * 16) = v;
        }
    }
    __syncthreads();

    for (int nh = 0; nh < 2; ++nh) {
        const signed char* Bw = Bd2 + (size_t)(nh * 64 + wave * 16 + col) * 576 + quad * 16;
        double cur = 0.0, vlt = 0.0;
        int spk = 0;
        unsigned bits = 0;
        double bias = (double)cb2[nh * 64 + oc_l];

        for (int mp = 0; mp < 4; ++mp) {
            v4i acc[5][2];
#pragma unroll
            for (int d = 0; d < 5; ++d) {
                acc[d][0] = (v4i){0, 0, 0, 0};
                acc[d][1] = (v4i){0, 0, 0, 0};
            }
#pragma unroll
            for (int ky = 0; ky < 3; ++ky) {
#pragma unroll
                for (int kx = 0; kx < 3; ++kx) {
                    const int kk = ky * 3 + kx;
                    const int p = (apy + ky) * 4 + (apxx + kx);
                    v4i Af0 = *(const v4i*)(As + (mp * 8 + tq) * 1040 + p * 64 + quad * 16);
                    v4i Af1 = *(const v4i*)(As + (mp * 8 + 4 + tq) * 1040 + p * 64 + quad * 16);
#pragma unroll
                    for (int d = 0; d < 5; ++d) {
                        v4i Bf = *(const v4i*)(Bw + d * 73728 + kk * 64);
                        acc[d][0] = __builtin_amdgcn_mfma_i32_16x16x64_i8(Af0, Bf, acc[d][0], 0, 0, 0);
                        acc[d][1] = __builtin_amdgcn_mfma_i32_16x16x64_i8(Af1, Bf, acc[d][1], 0, 0, 0);
                    }
                }
            }
            __syncthreads();                 // previous pl consumers done
#pragma unroll
            for (int j = 0; j < 2; ++j)
#pragma unroll
                for (int r = 0; r < 4; ++r) {
                    double p = 0.0;
#pragma unroll
                    for (int d = 0; d < 5; ++d)
                        p = fma((double)acc[d][j][r], scl[d], p);
                    pl[j][quad][r][wave * 16 + col] = p;   // row=quad*4+r -> t-sub=quad, px=r
                }
            __syncthreads();
#pragma unroll
            for (int j = 0; j < 2; ++j)
#pragma unroll
                for (int q = 0; q < 4; ++q) {
                    int t = (2 * mp + j) * 4 + q;
                    double z = bias + pl[j][q][px_e][oc_l];
                    cur = 0.5 * cur + z;
                    vlt = (spk ? 0.0 : 0.75 * vlt) + cur;
                    spk = (vlt > 0.5) ? 1 : 0;
                    bits |= ((unsigned)spk) << t;
                }
        }
        smask[px_e][oc_l] = bits;
        __syncthreads();
        {
            int tt = tid >> 6;               // 0..3
#pragma unroll
            for (int q = 0; q < 8; ++q) {
                int t = q * 4 + tt;
                unsigned s = ((smask[0][oc_l] >> t) & 1) + ((smask[1][oc_l] >> t) & 1)
                           + ((smask[2][oc_l] >> t) & 1) + ((smask[3][oc_l] >> t) & 1);
                pooled[(size_t)((w * 32 + t) * 256 + b) * 128 + nh * 64 + oc_l] = (unsigned char)s;
            }
        }
        __syncthreads();
    }
}

// ---------------- conv3 PSP: exact i8-digit GEMM, M=8192 N=256 K=1152 ----------
// grid 512 (M16 tiles) ; block 256 (4 waves x N64)
__global__ __launch_bounds__(256) void k_c3psp(const unsigned char* __restrict__ pooled,
        const signed char* __restrict__ Bd3, const float* __restrict__ b3,
        double* __restrict__ psp) {
    __shared__ __align__(16) unsigned char As[16 * 1168];   // row pad 16
    const int mt = blockIdx.x, rbase = mt * 16;
    const int tid = threadIdx.x;
    const int wave = tid >> 6, lane = tid & 63;
    const int col = lane & 15, quad = lane >> 4;
    for (int c = tid; c < 1152; c += 256) {       // 16 rows x 72 chunks
        int row = c / 72, cho = c - row * 72;
        int wn = cho >> 3, ico = (cho & 7) * 16;
        v4i v = *(const v4i*)(pooled + ((size_t)(wn * 8192) + rbase + row) * 128 + ico);
        *(v4i*)(As + row * 1168 + cho * 16) = v;
    }
    __syncthreads();
    const int nb = wave * 64;
    const double scl[5] = { 0x1p-40, 0x1p-32, 0x1p-24, 0x1p-16, 0x1p-8 };  // folds /4 pool
    double psum[4][4];
#pragma unroll
    for (int nt = 0; nt < 4; ++nt)
#pragma unroll
        for (int r = 0; r < 4; ++r) psum[nt][r] = 0.0;
    for (int d = 0; d < 5; ++d) {
        v4i acc[4];
#pragma unroll
        for (int nt = 0; nt < 4; ++nt) acc[nt] = (v4i){0, 0, 0, 0};
        for (int kk = 0; kk < 18; ++kk) {
            v4i Af = *(const v4i*)(As + (lane & 15) * 1168 + kk * 64 + quad * 16);
#pragma unroll
            for (int nt = 0; nt < 4; ++nt) {
                v4i Bf = *(const v4i*)(Bd3 + (size_t)d * 294912
                        + (size_t)(nb + nt * 16 + col) * 1152 + kk * 64 + quad * 16);
                acc[nt] = __builtin_amdgcn_mfma_i32_16x16x64_i8(Af, Bf, acc[nt], 0, 0, 0);
            }
        }
        double s = scl[d];
#pragma unroll
        for (int nt = 0; nt < 4; ++nt)
#pragma unroll
            for (int r = 0; r < 4; ++r)
                psum[nt][r] = fma((double)acc[nt][r], s, psum[nt][r]);
    }
#pragma unroll
    for (int nt = 0; nt < 4; ++nt) {
        double bias = (double)b3[nb + nt * 16 + col];
#pragma unroll
        for (int r = 0; r < 4; ++r) {
            int row = rbase + quad * 4 + r;
            psp[(size_t)row * 256 + nb + nt * 16 + col] = bias + psum[nt][r];
        }
    }
}

// ---------------- tc PSP: exact i8-digit GEMM, K=768 (3-tap history) ------------
__global__ __launch_bounds__(256) void k_tcpsp(const unsigned char* __restrict__ s3,
        const signed char* __restrict__ Bdtc, const float* __restrict__ tcb,
        double* __restrict__ psp) {
    __shared__ __align__(16) unsigned char As[16 * 784];
    const int mt = blockIdx.x, rbase = mt * 16;
    const int t = rbase >> 8;                      // constant per block
    const int tid = threadIdx.x;
    const int wave = tid >> 6, lane = tid & 63;
    const int col = lane & 15, quad = lane >> 4;
    for (int c = tid; c < 768; c += 256) {         // 16 rows x 48 chunks
        int row = c / 48, cho = c - row * 48;
        int j = cho >> 4, kc = (cho & 15) * 16;
        int bb = (rbase + row) & 255;
        int src = (t >= 2) ? (t - 2 + j) : ((j <= t) ? j : -1);  // j-th OLDEST tap
        v4i v = (v4i){0, 0, 0, 0};
        if (src >= 0) v = *(const v4i*)(s3 + ((size_t)(src * 256 + bb)) * 256 + kc);
        *(v4i*)(As + row * 784 + cho * 16) = v;
    }
    __syncthreads();
    const int nb = wave * 64;
    const double scl[5] = { 0x1p-38, 0x1p-30, 0x1p-22, 0x1p-14, 0x1p-6 };
    double psum[4][4];
#pragma unroll
    for (int nt = 0; nt < 4; ++nt)
#pragma unroll
        for (int r = 0; r < 4; ++r) psum[nt][r] = 0.0;
    for (int d = 0; d < 5; ++d) {
        v4i acc[4];
#pragma unroll
        for (int nt = 0; nt < 4; ++nt) acc[nt] = (v4i){0, 0, 0, 0};
        for (int kk = 0; kk < 12; ++kk) {
            v4i Af = *(const v4i*)(As + (lane & 15) * 784 + kk * 64 + quad * 16);
#pragma unroll
            for (int nt = 0; nt < 4; ++nt) {
                v4i Bf = *(const v4i*)(Bdtc + (size_t)d * 196608
                        + (size_t)(nb + nt * 16 + col) * 768 + kk * 64 + quad * 16);
                acc[nt] = __builtin_amdgcn_mfma_i32_16x16x64_i8(Af, Bf, acc[nt], 0, 0, 0);
            }
        }
        double s = scl[d];
#pragma unroll
        for (int nt = 0; nt < 4; ++nt)
#pragma unroll
            for (int r = 0; r < 4; ++r)
                psum[nt][r] = fma((double)acc[nt][r], s, psum[nt][r]);
    }
#pragma unroll
    for (int nt = 0; nt < 4; ++nt) {
        int n = nb + nt * 16 + col;
        double bias = (double)tcb[n];
        if (t >= 1) bias += (double)tcb[256 + n];
        if (t >= 2) bias += (double)tcb[512 + n];
#pragma unroll
        for (int r = 0; r < 4; ++r) {
            int row = rbase + quad * 4 + r;
            psp[(size_t)row * 256 + n] = bias + psum[nt][r];
        }
    }
}

// ---------------- sequential LIF sweep over [T][B*256] fp64 psp -> spikes -------
__global__ __launch_bounds__(256) void k_lif_flat(const double* __restrict__ psp,
        unsigned char* __restrict__ out) {
    int n = blockIdx.x * 256 + threadIdx.x;
    double cur = 0.0, vlt = 0.0;
    int spk = 0;
    for (int t = 0; t < T; ++t) {
        double z = psp[(size_t)t * 65536 + n];
        cur = 0.5 * cur + z;
        vlt = (spk ? 0.0 : 0.75 * vlt) + cur;
        spk = (vlt > 0.5) ? 1 : 0;
        out[(size_t)t * 65536 + n] = (unsigned char)spk;
    }
}

// ---------------- recurrent layer: dense fp64 matvec, weights in registers ------
__global__ __launch_bounds__(1024) void k_rec(const unsigned char* __restrict__ tcspk,
        const double* __restrict__ recwt, const float* __restrict__ rb,
        unsigned char* __restrict__ rspk) {
    __shared__ double rs[256];
    __shared__ double partial[4][256];
    int b  = blockIdx.x;
    int oc = threadIdx.x & 255;
    int ks = threadIdx.x >> 8;              // 0..3
    double wreg[64];
#pragma unroll
    for (int i = 0; i < 64; ++i)
        wreg[i] = recwt[(size_t)(ks * 64 + i) * 256 + oc];
    if (ks == 0) rs[oc] = 0.0;
    double bias = (double)rb[oc];
    double cur = 0.0, vlt = 0.0;
    int spk = 0;
    __syncthreads();
    for (int t = 0; t < T; ++t) {
        const double* rsk = &rs[ks * 64];
        double z0 = 0.0, z1 = 0.0;
#pragma unroll
        for (int i = 0; i < 64; i += 2) {
            z0 = fma(wreg[i],     rsk[i],     z0);
            z1 = fma(wreg[i + 1], rsk[i + 1], z1);
        }
        partial[ks][oc] = z0 + z1;
        __syncthreads();
        if (ks == 0) {
            double z = bias + (double)tcspk[((size_t)t * B + b) * 256 + oc]
                     + ((partial[0][oc] + partial[1][oc]) + (partial[2][oc] + partial[3][oc]));
            cur = 0.5 * cur + z;
            vlt = (spk ? 0.0 : 0.75 * vlt) + cur;
            spk = (vlt > 0.5) ? 1 : 0;
            rspk[((size_t)t * B + b) * 256 + oc] = (unsigned char)spk;
            rs[oc] = (double)spk;
        }
        __syncthreads();
    }
}

// ---------------- fc1 PSP: exact i8-digit GEMM, N=128 K=256 ----------------
__global__ __launch_bounds__(256) void k_f1psp(const unsigned char* __restrict__ rspk,
        const signed char* __restrict__ Bdf1, const float* __restrict__ f1b,
        double* __restrict__ psp) {
    __shared__ __align__(16) unsigned char As[16 * 272];
    const int mt = blockIdx.x, rbase = mt * 16;
    const int tid = threadIdx.x;
    const int wave = tid >> 6, lane = tid & 63;
    const int col = lane & 15, quad = lane >> 4;
    if (tid < 256) {                               // 16 rows x 16 chunks
        int row = tid >> 4, cho = tid & 15;
        v4i v = *(const v4i*)(rspk + (size_t)(rbase + row) * 256 + cho * 16);
        *(v4i*)(As + row * 272 + cho * 16) = v;
    }
    __syncthreads();
    const int nb = wave * 32;
    const double scl[5] = { 0x1p-38, 0x1p-30, 0x1p-22, 0x1p-14, 0x1p-6 };
    double psum[2][4];
#pragma unroll
    for (int nt = 0; nt < 2; ++nt)
#pragma unroll
        for (int r = 0; r < 4; ++r) psum[nt][r] = 0.0;
    for (int d = 0; d < 5; ++d) {
        v4i acc[2];
        acc[0] = (v4i){0, 0, 0, 0};
        acc[1] = (v4i){0, 0, 0, 0};
#pragma unroll
        for (int kk = 0; kk < 4; ++kk) {
            v4i Af = *(const v4i*)(As + (lane & 15) * 272 + kk * 64 + quad * 16);
#pragma unroll
            for (int nt = 0; nt < 2; ++nt) {
                v4i Bf = *(const v4i*)(Bdf1 + (size_t)d * 32768
                        + (size_t)(nb + nt * 16 + col) * 256 + kk * 64 + quad * 16);
                acc[nt] = __builtin_amdgcn_mfma_i32_16x16x64_i8(Af, Bf, acc[nt], 0, 0, 0);
            }
        }
        double s = scl[d];
#pragma unroll
        for (int nt = 0; nt < 2; ++nt)
#pragma unroll
            for (int r = 0; r < 4; ++r)
                psum[nt][r] = fma((double)acc[nt][r], s, psum[nt][r]);
    }
#pragma unroll
    for (int nt = 0; nt < 2; ++nt) {
        int n = nb + nt * 16 + col;
        double bias = (double)f1b[n];
#pragma unroll
        for (int r = 0; r < 4; ++r) {
            int row = rbase + quad * 4 + r;
            psp[(size_t)row * 128 + n] = bias + psum[nt][r];
        }
    }
}

// ---------------- fc1 LIF (registers) + fc2 via end-of-time reduction ----------
__global__ __launch_bounds__(128) void k_fc_out(const double* __restrict__ psp,
        const float* __restrict__ fc2w, const float* __restrict__ tsw,
        float* __restrict__ out) {
    __shared__ double sm[128];
    int b = blockIdx.x, oc = threadIdx.x;
    double ps[T];
#pragma unroll
    for (int t = 0; t < T; ++t)
        ps[t] = psp[((size_t)t * B + b) * 128 + oc];
    double cur = 0.0, vlt = 0.0, sAcc = 0.0;
    int spk = 0;
#pragma unroll
    for (int t = 0; t < T; ++t) {
        cur = 0.5 * cur + ps[t];
        vlt = (spk ? 0.0 : 0.75 * vlt) + cur;
        spk = (vlt > 0.5) ? 1 : 0;
        if (spk) sAcc += (double)tsw[t];
    }
    sm[oc] = sAcc;
    __syncthreads();
    if (oc < 2) {
        double s = 0.0;
        for (int k = 0; k < 128; ++k)
            s = fma(sm[k], (double)fc2w[oc * 128 + k], s);
        out[b * 2 + oc] = (float)s;
    }
}

extern "C" void kernel_launch(void* const* d_in, const int* in_sizes, int n_in,
                              void* d_out, int out_size, void* d_ws, size_t ws_size,
                              hipStream_t stream) {
    const float* x   = (const float*)d_in[0];
    const float* c1w = (const float*)d_in[1];
    const float* c1b = (const float*)d_in[2];
    const float* c2w = (const float*)d_in[3];
    const float* c2b = (const float*)d_in[4];
    const float* c3w = (const float*)d_in[5];
    const float* c3b = (const float*)d_in[6];
    const float* tcw = (const float*)d_in[7];
    const float* tcb = (const float*)d_in[8];
    const float* rcw = (const float*)d_in[9];
    const float* rcb = (const float*)d_in[10];
    const float* f1w = (const float*)d_in[11];
    const float* f1b = (const float*)d_in[12];
    const float* f2w = (const float*)d_in[13];
    const float* tsw = (const float*)d_in[14];

    char* ws = (char*)d_ws;
    signed char* Bd2      = (signed char*)(ws + OFF_BD2);
    signed char* Bd3      = (signed char*)(ws + OFF_BD3);
    signed char* Bdtc     = (signed char*)(ws + OFF_BDTC);
    signed char* Bdf1     = (signed char*)(ws + OFF_BDF1);
    double* recwt         = (double*)(ws + OFF_RECWT);
    unsigned char* s1     = (unsigned char*)(ws + OFF_S1);
    unsigned char* pool   = (unsigned char*)(ws + OFF_POOL);
    double* psp3          = (double*)(ws + OFF_PSP3);
    unsigned char* s3     = (unsigned char*)(ws + OFF_S3);
    double* psptc         = (double*)(ws + OFF_PSPTC);
    unsigned char* tcs    = (unsigned char*)(ws + OFF_TC);
    unsigned char* rsp    = (unsigned char*)(ws + OFF_R);
    double* pspf1         = (double*)(ws + OFF_PSPF1);

    k_prep    <<<256,  256, 0, stream>>>(rcw, recwt);
    k_prepd   <<<2336, 256, 0, stream>>>(c2w, c3w, tcw, f1w, Bd2, Bd3, Bdtc, Bdf1);
    k_conv1   <<<256,  256, 0, stream>>>(x, c1w, c1b, s1);
    k_conv2   <<<2304, 256, 0, stream>>>(s1, Bd2, c2b, pool);
    k_c3psp   <<<512,  256, 0, stream>>>(pool, Bd3, c3b, psp3);
    k_lif_flat<<<256,  256, 0, stream>>>(psp3, s3);
    k_tcpsp   <<<512,  256, 0, stream>>>(s3, Bdtc, tcb, psptc);
    k_lif_flat<<<256,  256, 0, stream>>>(psptc, tcs);
    k_rec     <<<256, 1024, 0, stream>>>(tcs, recwt, rcb, rsp);
    k_f1psp   <<<512,  256, 0, stream>>>(rsp, Bdf1, f1b, pspf1);
    k_fc_out  <<<256,  128, 0, stream>>>(pspf1, f2w, tsw, (float*)d_out);
}